// Round 4
// baseline (1373.814 us; speedup 1.0000x reference)
//
#include <hip/hip_runtime.h>
#include <hip/hip_bf16.h>
#include <math.h>

#define DIV_UP(a,b) (((a)+(b)-1)/(b))

// ---------------------------------------------------------------------------
// Graph prep: degrees, prefix scan -> rowptr, CSR scatter (+ deterministic sort)
// ---------------------------------------------------------------------------

__global__ void deg_kernel(const int* __restrict__ src, const int* __restrict__ dst,
                           int* __restrict__ deg_src, int* __restrict__ deg_dst, int E)
{
    int e = blockIdx.x * blockDim.x + threadIdx.x;
    if (e >= E) return;
    atomicAdd(&deg_src[src[e]], 1);
    atomicAdd(&deg_dst[dst[e]], 1);
}

// Block-level inclusive scan over chunks of 1024 ints (256 threads x 4).
__global__ void scanA_kernel(const int* __restrict__ deg, int* __restrict__ incl,
                             int* __restrict__ bsums, int n)
{
    __shared__ int sdata[256];
    int t = threadIdx.x;
    int base = blockIdx.x * 1024 + t * 4;
    int v[4];
    int s = 0;
#pragma unroll
    for (int i = 0; i < 4; i++) {
        int x = (base + i < n) ? deg[base + i] : 0;
        s += x;
        v[i] = s;                // inclusive within thread
    }
    sdata[t] = s;
    __syncthreads();
#pragma unroll
    for (int off = 1; off < 256; off <<= 1) {
        int x = (t >= off) ? sdata[t - off] : 0;
        __syncthreads();
        sdata[t] += x;
        __syncthreads();
    }
    int prev = (t > 0) ? sdata[t - 1] : 0;
#pragma unroll
    for (int i = 0; i < 4; i++)
        if (base + i < n) incl[base + i] = prev + v[i];
    if (t == 255) bsums[blockIdx.x] = sdata[255];
}

__global__ void scanB_kernel(const int* __restrict__ bsums, int* __restrict__ bsumex, int nblk)
{
    if (blockIdx.x == 0 && threadIdx.x == 0) {
        int run = 0;
        for (int i = 0; i < nblk; i++) { int v = bsums[i]; bsumex[i] = run; run += v; }
    }
}

__global__ void scanC_kernel(const int* __restrict__ incl, const int* __restrict__ deg,
                             const int* __restrict__ bsumex,
                             int* __restrict__ rowptr, int* __restrict__ cursor,
                             int n, int total)
{
    int i = blockIdx.x * blockDim.x + threadIdx.x;
    if (i > n) return;
    if (i == n) { rowptr[n] = total; return; }
    int r = incl[i] - deg[i] + bsumex[i >> 10];   // exclusive prefix
    rowptr[i] = r;
    cursor[i] = r;
}

__global__ void scatter_kernel(const int* __restrict__ src, const int* __restrict__ dst,
                               const int* __restrict__ deg_src, const int* __restrict__ deg_dst,
                               int* __restrict__ cursor,
                               int* __restrict__ csr_src, float* __restrict__ csr_norm, int E)
{
    int e = blockIdx.x * blockDim.x + threadIdx.x;
    if (e >= E) return;
    int s = src[e], d = dst[e];
    float ns = rsqrtf(fmaxf((float)deg_src[s], 1.f));
    float nd = rsqrtf(fmaxf((float)deg_dst[d], 1.f));
    int pos = atomicAdd(&cursor[d], 1);
    csr_src[pos]  = s;
    csr_norm[pos] = ns * nd;
}

// Canonicalize row order (atomic scatter order is nondeterministic run-to-run;
// fp32 sum order must be a pure function of the inputs). Insertion sort by src;
// duplicate srcs in a row have identical norm, so equal-key order is harmless.
__global__ void rowsort_kernel(const int* __restrict__ rowptr,
                               int* __restrict__ csr_src, float* __restrict__ csr_norm, int n)
{
    int node = blockIdx.x * blockDim.x + threadIdx.x;
    if (node >= n) return;
    int beg = rowptr[node], end = rowptr[node + 1];
    for (int i = beg + 1; i < end; ++i) {
        int key = csr_src[i];
        float w = csr_norm[i];
        int j = i - 1;
        while (j >= beg && csr_src[j] > key) {
            csr_src[j + 1] = csr_src[j];
            csr_norm[j + 1] = csr_norm[j];
            --j;
        }
        csr_src[j + 1] = key;
        csr_norm[j + 1] = w;
    }
}

// ---------------------------------------------------------------------------
// Propagation
// ---------------------------------------------------------------------------

__global__ void init_hidden_kernel(const float4* __restrict__ embed, float4* __restrict__ hidden,
                                   const float* __restrict__ temp, int n4)
{
    int i = blockIdx.x * blockDim.x + threadIdx.x;
    if (i >= n4) return;
    float t0 = temp[0];
    float4 v = embed[i];
    v.x *= t0; v.y *= t0; v.z *= t0; v.w *= t0;
    hidden[i] = v;
}

// One 32-lane group per node; lane owns one float4 chunk of the 128-d row.
// Pull-style segment sum over incoming edges (no atomics); fuses
// hidden += temp[k+1] * x_new.
__global__ void hop_kernel(const float* __restrict__ xin, float* __restrict__ xout,
                           float* __restrict__ hidden,
                           const int* __restrict__ rowptr, const int* __restrict__ csr_src,
                           const float* __restrict__ csr_norm,
                           const float* __restrict__ temp, int kidx, int n)
{
    int gid = blockIdx.x * blockDim.x + threadIdx.x;
    int node = gid >> 5;
    if (node >= n) return;
    int c = (gid & 31) * 4;
    float tk = temp[kidx];
    int beg = rowptr[node], end = rowptr[node + 1];
    float ax = 0.f, ay = 0.f, az = 0.f, aw = 0.f;
    for (int j = beg; j < end; ++j) {
        int   s = csr_src[j];
        float w = csr_norm[j];
        const float4 v = *reinterpret_cast<const float4*>(xin + (size_t)s * 128 + c);
        ax += w * v.x; ay += w * v.y; az += w * v.z; aw += w * v.w;
    }
    size_t o = (size_t)node * 128 + c;
    *reinterpret_cast<float4*>(xout + o) = make_float4(ax, ay, az, aw);
    float4* ph = reinterpret_cast<float4*>(hidden + o);
    float4 h = *ph;
    h.x += tk * ax; h.y += tk * ay; h.z += tk * az; h.w += tk * aw;
    *ph = h;
}

// ---------------------------------------------------------------------------
// Attention pooling
// ---------------------------------------------------------------------------

__global__ void segstart_kernel(const int* __restrict__ seg, int* __restrict__ out, int L, int B)
{
    int b = blockIdx.x * blockDim.x + threadIdx.x;
    if (b > B) return;
    int lo = 0, hi = L;
    while (lo < hi) { int mid = (lo + hi) >> 1; if (seg[mid] < b) lo = mid + 1; else hi = mid; }
    out[b] = lo;
}

// One 64-lane wave per pooled element: s[l] = dot(z[idx[l]], w) + b
__global__ void score_kernel(const float* __restrict__ z, const int* __restrict__ idx,
                             const float* __restrict__ attn_w, const float* __restrict__ attn_b,
                             float* __restrict__ s, int L)
{
    int gid = blockIdx.x * blockDim.x + threadIdx.x;
    int l = gid >> 6;
    if (l >= L) return;
    int lane = threadIdx.x & 63;
    int node = idx[l];
    const float2 v = *reinterpret_cast<const float2*>(z + (size_t)node * 128 + lane * 2);
    const float2 w = *reinterpret_cast<const float2*>(attn_w + lane * 2);
    float p = v.x * w.x + v.y * w.y;
#pragma unroll
    for (int off = 32; off > 0; off >>= 1) p += __shfl_down(p, off, 64);
    if (lane == 0) s[l] = p + attn_b[0];
}

// One 64-lane wave per segment: softmax over its elements, weighted row sum.
__global__ void pool_kernel(const float* __restrict__ z, const int* __restrict__ idx,
                            const float* __restrict__ s, const int* __restrict__ segstart,
                            float* __restrict__ out, int B)
{
    int gid = blockIdx.x * blockDim.x + threadIdx.x;
    int b = gid >> 6;
    if (b >= B) return;
    int lane = threadIdx.x & 63;
    int beg = segstart[b], end = segstart[b + 1];
    float accx = 0.f, accy = 0.f;
    if (end > beg) {
        float m = -1e30f;
        for (int j = beg; j < end; ++j) m = fmaxf(m, s[j]);
        float denom = 0.f;
        for (int j = beg; j < end; ++j) {
            float e = expf(s[j] - m);
            denom += e;
            int node = idx[j];
            const float2 v = *reinterpret_cast<const float2*>(z + (size_t)node * 128 + lane * 2);
            accx += e * v.x; accy += e * v.y;
        }
        float inv = 1.f / denom;
        accx *= inv; accy *= inv;
    }
    float2* po = reinterpret_cast<float2*>(out + (size_t)b * 128 + lane * 2);
    *po = make_float2(accx, accy);
}

// ---------------------------------------------------------------------------
// MLP: hid = relu([h,t,h*t] @ W1 + b1); out = hid @ W2 + b2
// ---------------------------------------------------------------------------

__global__ void gemm1_kernel(const float* __restrict__ hP, const float* __restrict__ tP,
                             const float* __restrict__ W1, const float* __restrict__ b1,
                             float* __restrict__ hid)
{
    const int N = 512;
    __shared__ float As[16][68];
    __shared__ float Bs[16][68];
    int tid = threadIdx.x;
    int tx = tid & 15, ty = tid >> 4;
    int n0 = blockIdx.x * 64, m0 = blockIdx.y * 64;
    float acc[4][4];
#pragma unroll
    for (int i = 0; i < 4; i++)
#pragma unroll
        for (int j = 0; j < 4; j++) acc[i][j] = 0.f;
    int coln = tid & 63, rk = tid >> 6;
    for (int kt = 0; kt < 384; kt += 16) {
        // A tile (feats on the fly): As[k][m_local]
#pragma unroll
        for (int i = 0; i < 4; i++) {
            int ml = ty + 16 * i;
            size_t m = (size_t)(m0 + ml);
            int k = kt + tx;
            float a;
            if (k < 128)      a = hP[m * 128 + k];
            else if (k < 256) a = tP[m * 128 + (k - 128)];
            else { int kk = k - 256; a = hP[m * 128 + kk] * tP[m * 128 + kk]; }
            As[tx][ml] = a;
        }
#pragma unroll
        for (int i = 0; i < 4; i++) {
            int kr = rk + 4 * i;
            Bs[kr][coln] = W1[(size_t)(kt + kr) * N + n0 + coln];
        }
        __syncthreads();
#pragma unroll
        for (int k = 0; k < 16; k++) {
            float a[4], bb[4];
#pragma unroll
            for (int i = 0; i < 4; i++) { a[i] = As[k][ty * 4 + i]; bb[i] = Bs[k][tx * 4 + i]; }
#pragma unroll
            for (int i = 0; i < 4; i++)
#pragma unroll
                for (int j = 0; j < 4; j++) acc[i][j] += a[i] * bb[j];
        }
        __syncthreads();
    }
#pragma unroll
    for (int i = 0; i < 4; i++) {
        int m = m0 + ty * 4 + i;
#pragma unroll
        for (int j = 0; j < 4; j++) {
            int nn = n0 + tx * 4 + j;
            float v = acc[i][j] + b1[nn];
            hid[(size_t)m * N + nn] = v > 0.f ? v : 0.f;
        }
    }
}

__global__ void gemm2_kernel(const float* __restrict__ A, const float* __restrict__ Bw,
                             const float* __restrict__ bias, float* __restrict__ out,
                             int KK, int Nn)
{
    __shared__ float As[16][68];
    __shared__ float Bs[16][68];
    int tid = threadIdx.x;
    int tx = tid & 15, ty = tid >> 4;
    int n0 = blockIdx.x * 64, m0 = blockIdx.y * 64;
    float acc[4][4];
#pragma unroll
    for (int i = 0; i < 4; i++)
#pragma unroll
        for (int j = 0; j < 4; j++) acc[i][j] = 0.f;
    int coln = tid & 63, rk = tid >> 6;
    for (int kt = 0; kt < KK; kt += 16) {
#pragma unroll
        for (int i = 0; i < 4; i++) {
            int ml = ty + 16 * i;
            As[tx][ml] = A[(size_t)(m0 + ml) * KK + kt + tx];
        }
#pragma unroll
        for (int i = 0; i < 4; i++) {
            int kr = rk + 4 * i;
            Bs[kr][coln] = (coln < Nn) ? Bw[(size_t)(kt + kr) * Nn + n0 + coln] : 0.f;
        }
        __syncthreads();
#pragma unroll
        for (int k = 0; k < 16; k++) {
            float a[4], bb[4];
#pragma unroll
            for (int i = 0; i < 4; i++) { a[i] = As[k][ty * 4 + i]; bb[i] = Bs[k][tx * 4 + i]; }
#pragma unroll
            for (int i = 0; i < 4; i++)
#pragma unroll
                for (int j = 0; j < 4; j++) acc[i][j] += a[i] * bb[j];
        }
        __syncthreads();
    }
#pragma unroll
    for (int i = 0; i < 4; i++) {
        int m = m0 + ty * 4 + i;
#pragma unroll
        for (int j = 0; j < 4; j++) {
            int nn = n0 + tx * 4 + j;
            if (nn < Nn) out[(size_t)m * Nn + nn] = acc[i][j] + bias[nn];
        }
    }
}

// ---------------------------------------------------------------------------

extern "C" void kernel_launch(void* const* d_in, const int* in_sizes, int n_in,
                              void* d_out, int out_size, void* d_ws, size_t ws_size,
                              hipStream_t stream)
{
    const float* embed  = (const float*)d_in[0];
    const float* temp   = (const float*)d_in[1];
    const float* attn_w = (const float*)d_in[2];
    const float* attn_b = (const float*)d_in[3];
    const float* W1     = (const float*)d_in[4];
    const float* b1     = (const float*)d_in[5];
    const float* W2     = (const float*)d_in[6];
    const float* b2     = (const float*)d_in[7];
    const int*   ei     = (const int*)d_in[8];
    const int*   H_idx  = (const int*)d_in[9];
    const int*   H_seg  = (const int*)d_in[10];
    const int*   T_idx  = (const int*)d_in[11];
    const int*   T_seg  = (const int*)d_in[12];

    const int D     = in_sizes[2];        // 128
    const int N     = in_sizes[0] / D;    // 100000
    const int Khops = in_sizes[1] - 1;    // 3
    const int E     = in_sizes[8] / 2;    // 1600000
    const int L     = in_sizes[9];        // 262144
    const int R     = in_sizes[7];        // 64
    const int HMLP  = in_sizes[5];        // 512
    const int Bb    = out_size / R;       // 32768

    const int* srcI = ei;
    const int* dstI = ei + E;

    // ---- workspace carve (256B aligned) ----
    char* ws = (char*)d_ws;
    size_t off = 0;
    auto carve = [&](size_t bytes) -> char* {
        char* p = ws + off;
        off += (bytes + 255) & ~(size_t)255;
        return p;
    };

    int nblk = DIV_UP(N, 1024);
    int*   deg_src  = (int*)carve((size_t)N * 4);
    int*   deg_dst  = (int*)carve((size_t)N * 4);
    int*   incl     = (int*)carve((size_t)N * 4);
    int*   bsums    = (int*)carve((size_t)nblk * 4);
    int*   bsumex   = (int*)carve((size_t)nblk * 4);
    int*   rowptr   = (int*)carve((size_t)(N + 1) * 4);
    int*   cursor   = (int*)carve((size_t)N * 4);
    int*   csr_src  = (int*)carve((size_t)E * 4);
    float* csr_norm = (float*)carve((size_t)E * 4);
    float* xA       = (float*)carve((size_t)N * D * 4);
    float* xB       = (float*)carve((size_t)N * D * 4);
    float* hiddenZ  = (float*)carve((size_t)N * D * 4);
    float* sH       = (float*)carve((size_t)L * 4);
    float* sT       = (float*)carve((size_t)L * 4);
    int*   segH     = (int*)carve((size_t)(Bb + 1) * 4);
    int*   segT     = (int*)carve((size_t)(Bb + 1) * 4);
    float* hPool    = (float*)carve((size_t)Bb * D * 4);
    float* tPool    = (float*)carve((size_t)Bb * D * 4);
    // hid [Bb x 512] overlaps xA..xB (free after propagation): 67MB <= 102MB
    float* hid      = xA;

    hipMemsetAsync(deg_src, 0, (size_t)N * 4, stream);
    hipMemsetAsync(deg_dst, 0, (size_t)N * 4, stream);

    deg_kernel<<<DIV_UP(E, 256), 256, 0, stream>>>(srcI, dstI, deg_src, deg_dst, E);
    scanA_kernel<<<nblk, 256, 0, stream>>>(deg_dst, incl, bsums, N);
    scanB_kernel<<<1, 64, 0, stream>>>(bsums, bsumex, nblk);
    scanC_kernel<<<DIV_UP(N + 1, 256), 256, 0, stream>>>(incl, deg_dst, bsumex, rowptr, cursor, N, E);
    scatter_kernel<<<DIV_UP(E, 256), 256, 0, stream>>>(srcI, dstI, deg_src, deg_dst, cursor,
                                                       csr_src, csr_norm, E);
    rowsort_kernel<<<DIV_UP(N, 256), 256, 0, stream>>>(rowptr, csr_src, csr_norm, N);
    init_hidden_kernel<<<DIV_UP(N * D / 4, 256), 256, 0, stream>>>(
        (const float4*)embed, (float4*)hiddenZ, temp, N * D / 4);

    const float* xin = embed;
    float* xout = xA;
    for (int k = 0; k < Khops; k++) {
        hop_kernel<<<DIV_UP(N * 32, 256), 256, 0, stream>>>(
            xin, xout, hiddenZ, rowptr, csr_src, csr_norm, temp, k + 1, N);
        xin  = xout;
        xout = (xout == xA) ? xB : xA;
    }

    segstart_kernel<<<DIV_UP(Bb + 1, 256), 256, 0, stream>>>(H_seg, segH, L, Bb);
    segstart_kernel<<<DIV_UP(Bb + 1, 256), 256, 0, stream>>>(T_seg, segT, L, Bb);
    score_kernel<<<DIV_UP(L * 64, 256), 256, 0, stream>>>(hiddenZ, H_idx, attn_w, attn_b, sH, L);
    score_kernel<<<DIV_UP(L * 64, 256), 256, 0, stream>>>(hiddenZ, T_idx, attn_w, attn_b, sT, L);
    pool_kernel<<<DIV_UP(Bb * 64, 256), 256, 0, stream>>>(hiddenZ, H_idx, sH, segH, hPool, Bb);
    pool_kernel<<<DIV_UP(Bb * 64, 256), 256, 0, stream>>>(hiddenZ, T_idx, sT, segT, tPool, Bb);

    gemm1_kernel<<<dim3(HMLP / 64, Bb / 64), 256, 0, stream>>>(hPool, tPool, W1, b1, hid);
    gemm2_kernel<<<dim3(DIV_UP(R, 64), Bb / 64), 256, 0, stream>>>(hid, W2, b2, (float*)d_out, HMLP, R);
}

// Round 7
// 1192.791 us; speedup vs baseline: 1.1518x; 1.1518x over previous
//
#include <hip/hip_runtime.h>
#include <hip/hip_bf16.h>
#include <math.h>

#define DIV_UP(a,b) (((a)+(b)-1)/(b))

typedef __attribute__((ext_vector_type(8))) short short8;
typedef __attribute__((ext_vector_type(4))) float floatx4;

static __device__ __forceinline__ unsigned short f2bf(float f)
{
    union { float f; unsigned int u; } v; v.f = f;
    unsigned int u = v.u;
    return (unsigned short)((u + 0x7fffu + ((u >> 16) & 1u)) >> 16);
}

// ---------------------------------------------------------------------------
// Graph prep: degrees, prefix scan -> rowptr, CSR scatter (+ deterministic sort)
// ---------------------------------------------------------------------------

__global__ void deg_kernel(const int* __restrict__ src, const int* __restrict__ dst,
                           int* __restrict__ deg_src, int* __restrict__ deg_dst, int E)
{
    int e = blockIdx.x * blockDim.x + threadIdx.x;
    if (e >= E) return;
    atomicAdd(&deg_src[src[e]], 1);
    atomicAdd(&deg_dst[dst[e]], 1);
}

// Block-level inclusive scan over chunks of 1024 ints (256 threads x 4).
__global__ void scanA_kernel(const int* __restrict__ deg, int* __restrict__ incl,
                             int* __restrict__ bsums, int n)
{
    __shared__ int sdata[256];
    int t = threadIdx.x;
    int base = blockIdx.x * 1024 + t * 4;
    int v[4];
    int s = 0;
#pragma unroll
    for (int i = 0; i < 4; i++) {
        int x = (base + i < n) ? deg[base + i] : 0;
        s += x;
        v[i] = s;                // inclusive within thread
    }
    sdata[t] = s;
    __syncthreads();
#pragma unroll
    for (int off = 1; off < 256; off <<= 1) {
        int x = (t >= off) ? sdata[t - off] : 0;
        __syncthreads();
        sdata[t] += x;
        __syncthreads();
    }
    int prev = (t > 0) ? sdata[t - 1] : 0;
#pragma unroll
    for (int i = 0; i < 4; i++)
        if (base + i < n) incl[base + i] = prev + v[i];
    if (t == 255) bsums[blockIdx.x] = sdata[255];
}

__global__ void scanB_kernel(const int* __restrict__ bsums, int* __restrict__ bsumex, int nblk)
{
    if (blockIdx.x == 0 && threadIdx.x == 0) {
        int run = 0;
        for (int i = 0; i < nblk; i++) { int v = bsums[i]; bsumex[i] = run; run += v; }
    }
}

__global__ void scanC_kernel(const int* __restrict__ incl, const int* __restrict__ deg,
                             const int* __restrict__ bsumex,
                             int* __restrict__ rowptr, int* __restrict__ cursor,
                             int n, int total)
{
    int i = blockIdx.x * blockDim.x + threadIdx.x;
    if (i > n) return;
    if (i == n) { rowptr[n] = total; return; }
    int r = incl[i] - deg[i] + bsumex[i >> 10];   // exclusive prefix
    rowptr[i] = r;
    cursor[i] = r;
}

__global__ void scatter_kernel(const int* __restrict__ src, const int* __restrict__ dst,
                               const int* __restrict__ deg_src, const int* __restrict__ deg_dst,
                               int* __restrict__ cursor,
                               int* __restrict__ csr_src, float* __restrict__ csr_norm, int E)
{
    int e = blockIdx.x * blockDim.x + threadIdx.x;
    if (e >= E) return;
    int s = src[e], d = dst[e];
    float ns = rsqrtf(fmaxf((float)deg_src[s], 1.f));
    float nd = rsqrtf(fmaxf((float)deg_dst[d], 1.f));
    int pos = atomicAdd(&cursor[d], 1);
    csr_src[pos]  = s;
    csr_norm[pos] = ns * nd;
}

// Canonicalize row order (atomic scatter order is nondeterministic run-to-run;
// fp32 sum order must be a pure function of the inputs).
__global__ void rowsort_kernel(const int* __restrict__ rowptr,
                               int* __restrict__ csr_src, float* __restrict__ csr_norm, int n)
{
    int node = blockIdx.x * blockDim.x + threadIdx.x;
    if (node >= n) return;
    int beg = rowptr[node], end = rowptr[node + 1];
    for (int i = beg + 1; i < end; ++i) {
        int key = csr_src[i];
        float w = csr_norm[i];
        int j = i - 1;
        while (j >= beg && csr_src[j] > key) {
            csr_src[j + 1] = csr_src[j];
            csr_norm[j + 1] = csr_norm[j];
            --j;
        }
        csr_src[j + 1] = key;
        csr_norm[j + 1] = w;
    }
}

// ---------------------------------------------------------------------------
// Propagation
// ---------------------------------------------------------------------------

__global__ void init_hidden_kernel(const float4* __restrict__ embed, float4* __restrict__ hidden,
                                   const float* __restrict__ temp, int n4)
{
    int i = blockIdx.x * blockDim.x + threadIdx.x;
    if (i >= n4) return;
    float t0 = temp[0];
    float4 v = embed[i];
    v.x *= t0; v.y *= t0; v.z *= t0; v.w *= t0;
    hidden[i] = v;
}

// One 32-lane group per node; lane owns one float4 chunk of the 128-d row.
__global__ void hop_kernel(const float* __restrict__ xin, float* __restrict__ xout,
                           float* __restrict__ hidden,
                           const int* __restrict__ rowptr, const int* __restrict__ csr_src,
                           const float* __restrict__ csr_norm,
                           const float* __restrict__ temp, int kidx, int n)
{
    int gid = blockIdx.x * blockDim.x + threadIdx.x;
    int node = gid >> 5;
    if (node >= n) return;
    int c = (gid & 31) * 4;
    float tk = temp[kidx];
    int beg = rowptr[node], end = rowptr[node + 1];
    float ax = 0.f, ay = 0.f, az = 0.f, aw = 0.f;
    for (int j = beg; j < end; ++j) {
        int   s = csr_src[j];
        float w = csr_norm[j];
        const float4 v = *reinterpret_cast<const float4*>(xin + (size_t)s * 128 + c);
        ax += w * v.x; ay += w * v.y; az += w * v.z; aw += w * v.w;
    }
    size_t o = (size_t)node * 128 + c;
    *reinterpret_cast<float4*>(xout + o) = make_float4(ax, ay, az, aw);
    float4* ph = reinterpret_cast<float4*>(hidden + o);
    float4 h = *ph;
    h.x += tk * ax; h.y += tk * ay; h.z += tk * az; h.w += tk * aw;
    *ph = h;
}

// ---------------------------------------------------------------------------
// Attention pooling
// ---------------------------------------------------------------------------

__global__ void segstart_kernel(const int* __restrict__ seg, int* __restrict__ out, int L, int B)
{
    int b = blockIdx.x * blockDim.x + threadIdx.x;
    if (b > B) return;
    int lo = 0, hi = L;
    while (lo < hi) { int mid = (lo + hi) >> 1; if (seg[mid] < b) lo = mid + 1; else hi = mid; }
    out[b] = lo;
}

__global__ void score_kernel(const float* __restrict__ z, const int* __restrict__ idx,
                             const float* __restrict__ attn_w, const float* __restrict__ attn_b,
                             float* __restrict__ s, int L)
{
    int gid = blockIdx.x * blockDim.x + threadIdx.x;
    int l = gid >> 6;
    if (l >= L) return;
    int lane = threadIdx.x & 63;
    int node = idx[l];
    const float2 v = *reinterpret_cast<const float2*>(z + (size_t)node * 128 + lane * 2);
    const float2 w = *reinterpret_cast<const float2*>(attn_w + lane * 2);
    float p = v.x * w.x + v.y * w.y;
#pragma unroll
    for (int off = 32; off > 0; off >>= 1) p += __shfl_down(p, off, 64);
    if (lane == 0) s[l] = p + attn_b[0];
}

__global__ void pool_kernel(const float* __restrict__ z, const int* __restrict__ idx,
                            const float* __restrict__ s, const int* __restrict__ segstart,
                            float* __restrict__ out, int B)
{
    int gid = blockIdx.x * blockDim.x + threadIdx.x;
    int b = gid >> 6;
    if (b >= B) return;
    int lane = threadIdx.x & 63;
    int beg = segstart[b], end = segstart[b + 1];
    float accx = 0.f, accy = 0.f;
    if (end > beg) {
        float m = -1e30f;
        for (int j = beg; j < end; ++j) m = fmaxf(m, s[j]);
        float denom = 0.f;
        for (int j = beg; j < end; ++j) {
            float e = expf(s[j] - m);
            denom += e;
            int node = idx[j];
            const float2 v = *reinterpret_cast<const float2*>(z + (size_t)node * 128 + lane * 2);
            accx += e * v.x; accy += e * v.y;
        }
        float inv = 1.f / denom;
        accx *= inv; accy *= inv;
    }
    float2* po = reinterpret_cast<float2*>(out + (size_t)b * 128 + lane * 2);
    *po = make_float2(accx, accy);
}

// ---------------------------------------------------------------------------
// MLP in bf16 MFMA: feats = [h,t,h*t] bf16; hid = relu(feats@W1+b1) bf16;
// out = hid@W2 + b2 (f32).
// ---------------------------------------------------------------------------

// src[K][N] f32 -> dst[N][K] bf16 (transpose + convert)
__global__ void convT_kernel(const float* __restrict__ src, unsigned short* __restrict__ dst,
                             int K, int N)
{
    int i = blockIdx.x * blockDim.x + threadIdx.x;
    if (i >= K * N) return;
    int k = i / N, n = i % N;
    dst[(size_t)n * K + k] = f2bf(src[i]);
}

__global__ void feats_kernel(const float* __restrict__ hP, const float* __restrict__ tP,
                             unsigned short* __restrict__ feats, int M)
{
    int i = blockIdx.x * blockDim.x + threadIdx.x;
    if (i >= M * 384) return;
    int m = i / 384, k = i % 384;
    float v;
    if (k < 128)      v = hP[(size_t)m * 128 + k];
    else if (k < 256) v = tP[(size_t)m * 128 + (k - 128)];
    else { int kk = k - 256; v = hP[(size_t)m * 128 + kk] * tP[(size_t)m * 128 + kk]; }
    feats[i] = f2bf(v);
}

// C[m][n] = relu(A[m][:] . BT[n][:] + bias[n]) -> bf16. A:[M][384], BT:[512][384].
// Block tile 128x64, 4 waves (2x2), wave tile 64x32 = 4x2 frags of 16x16x32.
__global__ __launch_bounds__(256) void gemm1_mfma(const unsigned short* __restrict__ A,
                                                  const unsigned short* __restrict__ Bt,
                                                  const float* __restrict__ bias,
                                                  unsigned short* __restrict__ C)
{
    const int K = 384;
    __shared__ short As[128][72];   // pad 64->72 shorts: 2-way bank alias only
    __shared__ short Bs[64][72];
    int tid = threadIdx.x;
    int lane = tid & 63, wave = tid >> 6;
    int wr = wave >> 1, wc = wave & 1;
    int m0 = blockIdx.y * 128, n0 = blockIdx.x * 64;
    int l15 = lane & 15, kg = (lane >> 4) * 8;

    floatx4 zero = {0.f, 0.f, 0.f, 0.f};
    floatx4 acc[4][2];
#pragma unroll
    for (int mi = 0; mi < 4; mi++)
#pragma unroll
        for (int ni = 0; ni < 2; ni++) acc[mi][ni] = zero;

    for (int kt = 0; kt < K; kt += 64) {
#pragma unroll
        for (int i = 0; i < 4; i++) {              // A tile: 128 rows x 64 k
            int c = tid + 256 * i;
            int row = c >> 3, ko = (c & 7) * 8;
            uint4 v = *reinterpret_cast<const uint4*>(A + (size_t)(m0 + row) * K + kt + ko);
            *reinterpret_cast<uint4*>(&As[row][ko]) = v;
        }
#pragma unroll
        for (int i = 0; i < 2; i++) {              // B tile: 64 rows x 64 k
            int c = tid + 256 * i;
            int row = c >> 3, ko = (c & 7) * 8;
            uint4 v = *reinterpret_cast<const uint4*>(Bt + (size_t)(n0 + row) * K + kt + ko);
            *reinterpret_cast<uint4*>(&Bs[row][ko]) = v;
        }
        __syncthreads();
#pragma unroll
        for (int ks = 0; ks < 2; ks++) {
            short8 b[2];
#pragma unroll
            for (int ni = 0; ni < 2; ni++)
                b[ni] = *reinterpret_cast<const short8*>(&Bs[wc * 32 + ni * 16 + l15][ks * 32 + kg]);
#pragma unroll
            for (int mi = 0; mi < 4; mi++) {
                short8 a = *reinterpret_cast<const short8*>(&As[wr * 64 + mi * 16 + l15][ks * 32 + kg]);
#pragma unroll
                for (int ni = 0; ni < 2; ni++)
                    acc[mi][ni] = __builtin_amdgcn_mfma_f32_16x16x32_bf16(a, b[ni], acc[mi][ni], 0, 0, 0);
            }
        }
        __syncthreads();
    }
    int rbase = (lane >> 4) * 4;
#pragma unroll
    for (int mi = 0; mi < 4; mi++)
#pragma unroll
        for (int ni = 0; ni < 2; ni++) {
            int n = n0 + wc * 32 + ni * 16 + l15;
            float bn = bias[n];
#pragma unroll
            for (int r = 0; r < 4; r++) {
                int m = m0 + wr * 64 + mi * 16 + rbase + r;
                float v = acc[mi][ni][r] + bn;
                v = v > 0.f ? v : 0.f;
                C[(size_t)m * 512 + n] = f2bf(v);
            }
        }
}

// out[m][n] = A[m][:] . BT[n][:] + bias[n] (f32). A:[M][512] bf16, BT:[64][512] bf16.
__global__ __launch_bounds__(256) void gemm2_mfma(const unsigned short* __restrict__ A,
                                                  const unsigned short* __restrict__ Bt,
                                                  const float* __restrict__ bias,
                                                  float* __restrict__ out)
{
    const int K = 512;
    __shared__ short As[128][72];
    __shared__ short Bs[64][72];
    int tid = threadIdx.x;
    int lane = tid & 63, wave = tid >> 6;
    int wr = wave >> 1, wc = wave & 1;
    int m0 = blockIdx.y * 128, n0 = 0;
    int l15 = lane & 15, kg = (lane >> 4) * 8;

    floatx4 zero = {0.f, 0.f, 0.f, 0.f};
    floatx4 acc[4][2];
#pragma unroll
    for (int mi = 0; mi < 4; mi++)
#pragma unroll
        for (int ni = 0; ni < 2; ni++) acc[mi][ni] = zero;

    for (int kt = 0; kt < K; kt += 64) {
#pragma unroll
        for (int i = 0; i < 4; i++) {
            int c = tid + 256 * i;
            int row = c >> 3, ko = (c & 7) * 8;
            uint4 v = *reinterpret_cast<const uint4*>(A + (size_t)(m0 + row) * K + kt + ko);
            *reinterpret_cast<uint4*>(&As[row][ko]) = v;
        }
#pragma unroll
        for (int i = 0; i < 2; i++) {
            int c = tid + 256 * i;
            int row = c >> 3, ko = (c & 7) * 8;
            uint4 v = *reinterpret_cast<const uint4*>(Bt + (size_t)(n0 + row) * K + kt + ko);
            *reinterpret_cast<uint4*>(&Bs[row][ko]) = v;
        }
        __syncthreads();
#pragma unroll
        for (int ks = 0; ks < 2; ks++) {
            short8 b[2];
#pragma unroll
            for (int ni = 0; ni < 2; ni++)
                b[ni] = *reinterpret_cast<const short8*>(&Bs[wc * 32 + ni * 16 + l15][ks * 32 + kg]);
#pragma unroll
            for (int mi = 0; mi < 4; mi++) {
                short8 a = *reinterpret_cast<const short8*>(&As[wr * 64 + mi * 16 + l15][ks * 32 + kg]);
#pragma unroll
                for (int ni = 0; ni < 2; ni++)
                    acc[mi][ni] = __builtin_amdgcn_mfma_f32_16x16x32_bf16(a, b[ni], acc[mi][ni], 0, 0, 0);
            }
        }
        __syncthreads();
    }
    int rbase = (lane >> 4) * 4;
#pragma unroll
    for (int mi = 0; mi < 4; mi++)
#pragma unroll
        for (int ni = 0; ni < 2; ni++) {
            int n = wc * 32 + ni * 16 + l15;
            float bn = bias[n];
#pragma unroll
            for (int r = 0; r < 4; r++) {
                int m = m0 + wr * 64 + mi * 16 + rbase + r;
                out[(size_t)m * 64 + n] = acc[mi][ni][r] + bn;
            }
        }
}

// ---------------------------------------------------------------------------

extern "C" void kernel_launch(void* const* d_in, const int* in_sizes, int n_in,
                              void* d_out, int out_size, void* d_ws, size_t ws_size,
                              hipStream_t stream)
{
    const float* embed  = (const float*)d_in[0];
    const float* temp   = (const float*)d_in[1];
    const float* attn_w = (const float*)d_in[2];
    const float* attn_b = (const float*)d_in[3];
    const float* W1     = (const float*)d_in[4];
    const float* b1     = (const float*)d_in[5];
    const float* W2     = (const float*)d_in[6];
    const float* b2     = (const float*)d_in[7];
    const int*   ei     = (const int*)d_in[8];
    const int*   H_idx  = (const int*)d_in[9];
    const int*   H_seg  = (const int*)d_in[10];
    const int*   T_idx  = (const int*)d_in[11];
    const int*   T_seg  = (const int*)d_in[12];

    const int D     = in_sizes[2];        // 128
    const int N     = in_sizes[0] / D;    // 100000
    const int Khops = in_sizes[1] - 1;    // 3
    const int E     = in_sizes[8] / 2;    // 1600000
    const int L     = in_sizes[9];        // 262144
    const int R     = in_sizes[7];        // 64
    const int HMLP  = in_sizes[5];        // 512
    const int Bb    = out_size / R;       // 32768

    const int* srcI = ei;
    const int* dstI = ei + E;

    // ---- workspace carve (256B aligned) ----
    char* ws = (char*)d_ws;
    size_t off = 0;
    auto carve = [&](size_t bytes) -> char* {
        char* p = ws + off;
        off += (bytes + 255) & ~(size_t)255;
        return p;
    };

    int nblk = DIV_UP(N, 1024);
    int*   deg_src  = (int*)carve((size_t)N * 4);
    int*   deg_dst  = (int*)carve((size_t)N * 4);
    int*   incl     = (int*)carve((size_t)N * 4);
    int*   bsums    = (int*)carve((size_t)nblk * 4);
    int*   bsumex   = (int*)carve((size_t)nblk * 4);
    int*   rowptr   = (int*)carve((size_t)(N + 1) * 4);
    int*   cursor   = (int*)carve((size_t)N * 4);
    int*   csr_src  = (int*)carve((size_t)E * 4);
    float* csr_norm = (float*)carve((size_t)E * 4);
    float* xA       = (float*)carve((size_t)N * D * 4);
    float* xB       = (float*)carve((size_t)N * D * 4);
    float* hiddenZ  = (float*)carve((size_t)N * D * 4);
    float* sH       = (float*)carve((size_t)L * 4);
    float* sT       = (float*)carve((size_t)L * 4);
    int*   segH     = (int*)carve((size_t)(Bb + 1) * 4);
    int*   segT     = (int*)carve((size_t)(Bb + 1) * 4);
    float* hPool    = (float*)carve((size_t)Bb * D * 4);
    float* tPool    = (float*)carve((size_t)Bb * D * 4);
    unsigned short* W1Tb = (unsigned short*)carve((size_t)HMLP * 384 * 2);
    unsigned short* W2Tb = (unsigned short*)carve((size_t)R * HMLP * 2);
    // bf16 feats [Bb x 384] (25.2MB) and hid [Bb x 512] (33.6MB) overlap the
    // x ping-pong buffers, which are dead after the last hop (each 51.2MB).
    unsigned short* featsB = (unsigned short*)xB;
    unsigned short* hidB   = (unsigned short*)xA;

    hipMemsetAsync(deg_src, 0, (size_t)N * 4, stream);
    hipMemsetAsync(deg_dst, 0, (size_t)N * 4, stream);

    deg_kernel<<<DIV_UP(E, 256), 256, 0, stream>>>(srcI, dstI, deg_src, deg_dst, E);
    scanA_kernel<<<nblk, 256, 0, stream>>>(deg_dst, incl, bsums, N);
    scanB_kernel<<<1, 64, 0, stream>>>(bsums, bsumex, nblk);
    scanC_kernel<<<DIV_UP(N + 1, 256), 256, 0, stream>>>(incl, deg_dst, bsumex, rowptr, cursor, N, E);
    scatter_kernel<<<DIV_UP(E, 256), 256, 0, stream>>>(srcI, dstI, deg_src, deg_dst, cursor,
                                                       csr_src, csr_norm, E);
    rowsort_kernel<<<DIV_UP(N, 256), 256, 0, stream>>>(rowptr, csr_src, csr_norm, N);
    init_hidden_kernel<<<DIV_UP(N * D / 4, 256), 256, 0, stream>>>(
        (const float4*)embed, (float4*)hiddenZ, temp, N * D / 4);

    const float* xin = embed;
    float* xout = xA;
    for (int k = 0; k < Khops; k++) {
        hop_kernel<<<DIV_UP(N * 32, 256), 256, 0, stream>>>(
            xin, xout, hiddenZ, rowptr, csr_src, csr_norm, temp, k + 1, N);
        xin  = xout;
        xout = (xout == xA) ? xB : xA;
    }
    // after 3 hops: xA holds x_3, xB holds x_2 -> both dead below.

    segstart_kernel<<<DIV_UP(Bb + 1, 256), 256, 0, stream>>>(H_seg, segH, L, Bb);
    segstart_kernel<<<DIV_UP(Bb + 1, 256), 256, 0, stream>>>(T_seg, segT, L, Bb);
    score_kernel<<<DIV_UP(L * 64, 256), 256, 0, stream>>>(hiddenZ, H_idx, attn_w, attn_b, sH, L);
    score_kernel<<<DIV_UP(L * 64, 256), 256, 0, stream>>>(hiddenZ, T_idx, attn_w, attn_b, sT, L);
    pool_kernel<<<DIV_UP(Bb * 64, 256), 256, 0, stream>>>(hiddenZ, H_idx, sH, segH, hPool, Bb);
    pool_kernel<<<DIV_UP(Bb * 64, 256), 256, 0, stream>>>(hiddenZ, T_idx, sT, segT, tPool, Bb);

    convT_kernel<<<DIV_UP(384 * HMLP, 256), 256, 0, stream>>>(W1, W1Tb, 384, HMLP);
    convT_kernel<<<DIV_UP(HMLP * R, 256), 256, 0, stream>>>(W2, W2Tb, HMLP, R);
    feats_kernel<<<DIV_UP(Bb * 384, 256), 256, 0, stream>>>(hPool, tPool, featsB, Bb);

    gemm1_mfma<<<dim3(HMLP / 64, Bb / 128), 256, 0, stream>>>(featsB, W1Tb, b1, hidB);
    gemm2_mfma<<<dim3(1, Bb / 128), 256, 0, stream>>>(hidB, W2Tb, b2, (float*)d_out);
}

// Round 12
// 1055.347 us; speedup vs baseline: 1.3018x; 1.1302x over previous
//
#include <hip/hip_runtime.h>
#include <hip/hip_bf16.h>
#include <math.h>

#define DIV_UP(a,b) (((a)+(b)-1)/(b))

typedef __attribute__((ext_vector_type(8))) short short8;
typedef __attribute__((ext_vector_type(4))) float floatx4;

static __device__ __forceinline__ unsigned short f2bf(float f)
{
    union { float f; unsigned int u; } v; v.f = f;
    unsigned int u = v.u;
    return (unsigned short)((u + 0x7fffu + ((u >> 16) & 1u)) >> 16);
}

// ---------------------------------------------------------------------------
// Graph prep: degrees, prefix scan -> rowptr, CSR scatter (+ deterministic sort)
// ---------------------------------------------------------------------------

__global__ void deg_kernel(const int* __restrict__ src, const int* __restrict__ dst,
                           int* __restrict__ deg_src, int* __restrict__ deg_dst, int E)
{
    int e = blockIdx.x * blockDim.x + threadIdx.x;
    if (e >= E) return;
    atomicAdd(&deg_src[src[e]], 1);
    atomicAdd(&deg_dst[dst[e]], 1);
}

// Block-level inclusive scan over chunks of 1024 ints (256 threads x 4).
__global__ void scanA_kernel(const int* __restrict__ deg, int* __restrict__ incl,
                             int* __restrict__ bsums, int n)
{
    __shared__ int sdata[256];
    int t = threadIdx.x;
    int base = blockIdx.x * 1024 + t * 4;
    int v[4];
    int s = 0;
#pragma unroll
    for (int i = 0; i < 4; i++) {
        int x = (base + i < n) ? deg[base + i] : 0;
        s += x;
        v[i] = s;                // inclusive within thread
    }
    sdata[t] = s;
    __syncthreads();
#pragma unroll
    for (int off = 1; off < 256; off <<= 1) {
        int x = (t >= off) ? sdata[t - off] : 0;
        __syncthreads();
        sdata[t] += x;
        __syncthreads();
    }
    int prev = (t > 0) ? sdata[t - 1] : 0;
#pragma unroll
    for (int i = 0; i < 4; i++)
        if (base + i < n) incl[base + i] = prev + v[i];
    if (t == 255) bsums[blockIdx.x] = sdata[255];
}

__global__ void scanB_kernel(const int* __restrict__ bsums, int* __restrict__ bsumex, int nblk)
{
    if (blockIdx.x == 0 && threadIdx.x == 0) {
        int run = 0;
        for (int i = 0; i < nblk; i++) { int v = bsums[i]; bsumex[i] = run; run += v; }
    }
}

__global__ void scanC_kernel(const int* __restrict__ incl, const int* __restrict__ deg,
                             const int* __restrict__ bsumex,
                             int* __restrict__ rowptr, int* __restrict__ cursor,
                             int n, int total)
{
    int i = blockIdx.x * blockDim.x + threadIdx.x;
    if (i > n) return;
    if (i == n) { rowptr[n] = total; return; }
    int r = incl[i] - deg[i] + bsumex[i >> 10];   // exclusive prefix
    rowptr[i] = r;
    cursor[i] = r;
}

__global__ void scatter_kernel(const int* __restrict__ src, const int* __restrict__ dst,
                               const int* __restrict__ deg_src, const int* __restrict__ deg_dst,
                               int* __restrict__ cursor,
                               int* __restrict__ csr_src, float* __restrict__ csr_norm, int E)
{
    int e = blockIdx.x * blockDim.x + threadIdx.x;
    if (e >= E) return;
    int s = src[e], d = dst[e];
    float ns = rsqrtf(fmaxf((float)deg_src[s], 1.f));
    float nd = rsqrtf(fmaxf((float)deg_dst[d], 1.f));
    int pos = atomicAdd(&cursor[d], 1);
    csr_src[pos]  = s;
    csr_norm[pos] = ns * nd;
}

// Canonicalize row order (atomic scatter order is nondeterministic run-to-run;
// fp32 sum order must be a pure function of the inputs). One 64-lane wave per
// row: lane i holds element i, rank = #{j : key_j < key_i or (== and j < i)}
// via wave-uniform deg-iteration shfl loop; write to beg+rank. Ranks unique
// (tie-break by lane); duplicate srcs carry identical norm so equal-key order
// is numerically irrelevant. Reads complete before writes (lockstep wave,
// program order). deg>64 falls back to lane-0 insertion sort (never taken at
// Poisson lambda=16, kept for safety).
__global__ void rowsort_kernel(const int* __restrict__ rowptr,
                               int* __restrict__ csr_src, float* __restrict__ csr_norm, int n)
{
    int wid = (blockIdx.x * blockDim.x + threadIdx.x) >> 6;
    if (wid >= n) return;
    int lane = threadIdx.x & 63;
    int beg = rowptr[wid], end = rowptr[wid + 1];
    int deg = end - beg;
    if (deg <= 1) return;
    if (deg <= 64) {
        int   key = (lane < deg) ? csr_src[beg + lane]  : 0x7fffffff;
        float w   = (lane < deg) ? csr_norm[beg + lane] : 0.f;
        int rank = 0;
        for (int j = 0; j < deg; j++) {           // deg is wave-uniform
            int kj = __shfl(key, j, 64);
            rank += (kj < key) || (kj == key && j < lane);
        }
        if (lane < deg) {
            csr_src[beg + rank]  = key;
            csr_norm[beg + rank] = w;
        }
    } else if (lane == 0) {
        for (int i = beg + 1; i < end; ++i) {
            int key = csr_src[i];
            float w = csr_norm[i];
            int j = i - 1;
            while (j >= beg && csr_src[j] > key) {
                csr_src[j + 1] = csr_src[j];
                csr_norm[j + 1] = csr_norm[j];
                --j;
            }
            csr_src[j + 1] = key;
            csr_norm[j + 1] = w;
        }
    }
}

// ---------------------------------------------------------------------------
// Propagation
// ---------------------------------------------------------------------------

__global__ void init_hidden_kernel(const float4* __restrict__ embed, float4* __restrict__ hidden,
                                   const float* __restrict__ temp, int n4)
{
    int i = blockIdx.x * blockDim.x + threadIdx.x;
    if (i >= n4) return;
    float t0 = temp[0];
    float4 v = embed[i];
    v.x *= t0; v.y *= t0; v.z *= t0; v.w *= t0;
    hidden[i] = v;
}

// One 32-lane group per node; lane owns one float4 chunk of the 128-d row.
__global__ void hop_kernel(const float* __restrict__ xin, float* __restrict__ xout,
                           float* __restrict__ hidden,
                           const int* __restrict__ rowptr, const int* __restrict__ csr_src,
                           const float* __restrict__ csr_norm,
                           const float* __restrict__ temp, int kidx, int n)
{
    int gid = blockIdx.x * blockDim.x + threadIdx.x;
    int node = gid >> 5;
    if (node >= n) return;
    int c = (gid & 31) * 4;
    float tk = temp[kidx];
    int beg = rowptr[node], end = rowptr[node + 1];
    float ax = 0.f, ay = 0.f, az = 0.f, aw = 0.f;
    for (int j = beg; j < end; ++j) {
        int   s = csr_src[j];
        float w = csr_norm[j];
        const float4 v = *reinterpret_cast<const float4*>(xin + (size_t)s * 128 + c);
        ax += w * v.x; ay += w * v.y; az += w * v.z; aw += w * v.w;
    }
    size_t o = (size_t)node * 128 + c;
    *reinterpret_cast<float4*>(xout + o) = make_float4(ax, ay, az, aw);
    float4* ph = reinterpret_cast<float4*>(hidden + o);
    float4 h = *ph;
    h.x += tk * ax; h.y += tk * ay; h.z += tk * az; h.w += tk * aw;
    *ph = h;
}

// ---------------------------------------------------------------------------
// Attention pooling
// ---------------------------------------------------------------------------

__global__ void segstart_kernel(const int* __restrict__ seg, int* __restrict__ out, int L, int B)
{
    int b = blockIdx.x * blockDim.x + threadIdx.x;
    if (b > B) return;
    int lo = 0, hi = L;
    while (lo < hi) { int mid = (lo + hi) >> 1; if (seg[mid] < b) lo = mid + 1; else hi = mid; }
    out[b] = lo;
}

__global__ void score_kernel(const float* __restrict__ z, const int* __restrict__ idx,
                             const float* __restrict__ attn_w, const float* __restrict__ attn_b,
                             float* __restrict__ s, int L)
{
    int gid = blockIdx.x * blockDim.x + threadIdx.x;
    int l = gid >> 6;
    if (l >= L) return;
    int lane = threadIdx.x & 63;
    int node = idx[l];
    const float2 v = *reinterpret_cast<const float2*>(z + (size_t)node * 128 + lane * 2);
    const float2 w = *reinterpret_cast<const float2*>(attn_w + lane * 2);
    float p = v.x * w.x + v.y * w.y;
#pragma unroll
    for (int off = 32; off > 0; off >>= 1) p += __shfl_down(p, off, 64);
    if (lane == 0) s[l] = p + attn_b[0];
}

__global__ void pool_kernel(const float* __restrict__ z, const int* __restrict__ idx,
                            const float* __restrict__ s, const int* __restrict__ segstart,
                            float* __restrict__ out, int B)
{
    int gid = blockIdx.x * blockDim.x + threadIdx.x;
    int b = gid >> 6;
    if (b >= B) return;
    int lane = threadIdx.x & 63;
    int beg = segstart[b], end = segstart[b + 1];
    float accx = 0.f, accy = 0.f;
    if (end > beg) {
        float m = -1e30f;
        for (int j = beg; j < end; ++j) m = fmaxf(m, s[j]);
        float denom = 0.f;
        for (int j = beg; j < end; ++j) {
            float e = expf(s[j] - m);
            denom += e;
            int node = idx[j];
            const float2 v = *reinterpret_cast<const float2*>(z + (size_t)node * 128 + lane * 2);
            accx += e * v.x; accy += e * v.y;
        }
        float inv = 1.f / denom;
        accx *= inv; accy *= inv;
    }
    float2* po = reinterpret_cast<float2*>(out + (size_t)b * 128 + lane * 2);
    *po = make_float2(accx, accy);
}

// ---------------------------------------------------------------------------
// MLP in bf16 MFMA: feats = [h,t,h*t] bf16; hid = relu(feats@W1+b1) bf16;
// out = hid@W2 + b2 (f32).
// ---------------------------------------------------------------------------

// src[K][N] f32 -> dst[N][K] bf16 (transpose + convert)
__global__ void convT_kernel(const float* __restrict__ src, unsigned short* __restrict__ dst,
                             int K, int N)
{
    int i = blockIdx.x * blockDim.x + threadIdx.x;
    if (i >= K * N) return;
    int k = i / N, n = i % N;
    dst[(size_t)n * K + k] = f2bf(src[i]);
}

__global__ void feats_kernel(const float* __restrict__ hP, const float* __restrict__ tP,
                             unsigned short* __restrict__ feats, int M)
{
    int i = blockIdx.x * blockDim.x + threadIdx.x;
    if (i >= M * 384) return;
    int m = i / 384, k = i % 384;
    float v;
    if (k < 128)      v = hP[(size_t)m * 128 + k];
    else if (k < 256) v = tP[(size_t)m * 128 + (k - 128)];
    else { int kk = k - 256; v = hP[(size_t)m * 128 + kk] * tP[(size_t)m * 128 + kk]; }
    feats[i] = f2bf(v);
}

// C[m][n] = relu(A[m][:] . BT[n][:] + bias[n]) -> bf16. A:[M][384], BT:[512][384].
// Block tile 128x64, 4 waves (2x2), wave tile 64x32 = 4x2 frags of 16x16x32.
__global__ __launch_bounds__(256) void gemm1_mfma(const unsigned short* __restrict__ A,
                                                  const unsigned short* __restrict__ Bt,
                                                  const float* __restrict__ bias,
                                                  unsigned short* __restrict__ C)
{
    const int K = 384;
    __shared__ short As[128][72];   // pad 64->72 shorts: 2-way bank alias only
    __shared__ short Bs[64][72];
    int tid = threadIdx.x;
    int lane = tid & 63, wave = tid >> 6;
    int wr = wave >> 1, wc = wave & 1;
    int m0 = blockIdx.y * 128, n0 = blockIdx.x * 64;
    int l15 = lane & 15, kg = (lane >> 4) * 8;

    floatx4 zero = {0.f, 0.f, 0.f, 0.f};
    floatx4 acc[4][2];
#pragma unroll
    for (int mi = 0; mi < 4; mi++)
#pragma unroll
        for (int ni = 0; ni < 2; ni++) acc[mi][ni] = zero;

    for (int kt = 0; kt < K; kt += 64) {
#pragma unroll
        for (int i = 0; i < 4; i++) {              // A tile: 128 rows x 64 k
            int c = tid + 256 * i;
            int row = c >> 3, ko = (c & 7) * 8;
            uint4 v = *reinterpret_cast<const uint4*>(A + (size_t)(m0 + row) * K + kt + ko);
            *reinterpret_cast<uint4*>(&As[row][ko]) = v;
        }
#pragma unroll
        for (int i = 0; i < 2; i++) {              // B tile: 64 rows x 64 k
            int c = tid + 256 * i;
            int row = c >> 3, ko = (c & 7) * 8;
            uint4 v = *reinterpret_cast<const uint4*>(Bt + (size_t)(n0 + row) * K + kt + ko);
            *reinterpret_cast<uint4*>(&Bs[row][ko]) = v;
        }
        __syncthreads();
#pragma unroll
        for (int ks = 0; ks < 2; ks++) {
            short8 b[2];
#pragma unroll
            for (int ni = 0; ni < 2; ni++)
                b[ni] = *reinterpret_cast<const short8*>(&Bs[wc * 32 + ni * 16 + l15][ks * 32 + kg]);
#pragma unroll
            for (int mi = 0; mi < 4; mi++) {
                short8 a = *reinterpret_cast<const short8*>(&As[wr * 64 + mi * 16 + l15][ks * 32 + kg]);
#pragma unroll
                for (int ni = 0; ni < 2; ni++)
                    acc[mi][ni] = __builtin_amdgcn_mfma_f32_16x16x32_bf16(a, b[ni], acc[mi][ni], 0, 0, 0);
            }
        }
        __syncthreads();
    }
    int rbase = (lane >> 4) * 4;
#pragma unroll
    for (int mi = 0; mi < 4; mi++)
#pragma unroll
        for (int ni = 0; ni < 2; ni++) {
            int n = n0 + wc * 32 + ni * 16 + l15;
            float bn = bias[n];
#pragma unroll
            for (int r = 0; r < 4; r++) {
                int m = m0 + wr * 64 + mi * 16 + rbase + r;
                float v = acc[mi][ni][r] + bn;
                v = v > 0.f ? v : 0.f;
                C[(size_t)m * 512 + n] = f2bf(v);
            }
        }
}

// out[m][n] = A[m][:] . BT[n][:] + bias[n] (f32). A:[M][512] bf16, BT:[64][512] bf16.
__global__ __launch_bounds__(256) void gemm2_mfma(const unsigned short* __restrict__ A,
                                                  const unsigned short* __restrict__ Bt,
                                                  const float* __restrict__ bias,
                                                  float* __restrict__ out)
{
    const int K = 512;
    __shared__ short As[128][72];
    __shared__ short Bs[64][72];
    int tid = threadIdx.x;
    int lane = tid & 63, wave = tid >> 6;
    int wr = wave >> 1, wc = wave & 1;
    int m0 = blockIdx.y * 128, n0 = 0;
    int l15 = lane & 15, kg = (lane >> 4) * 8;

    floatx4 zero = {0.f, 0.f, 0.f, 0.f};
    floatx4 acc[4][2];
#pragma unroll
    for (int mi = 0; mi < 4; mi++)
#pragma unroll
        for (int ni = 0; ni < 2; ni++) acc[mi][ni] = zero;

    for (int kt = 0; kt < K; kt += 64) {
#pragma unroll
        for (int i = 0; i < 4; i++) {
            int c = tid + 256 * i;
            int row = c >> 3, ko = (c & 7) * 8;
            uint4 v = *reinterpret_cast<const uint4*>(A + (size_t)(m0 + row) * K + kt + ko);
            *reinterpret_cast<uint4*>(&As[row][ko]) = v;
        }
#pragma unroll
        for (int i = 0; i < 2; i++) {
            int c = tid + 256 * i;
            int row = c >> 3, ko = (c & 7) * 8;
            uint4 v = *reinterpret_cast<const uint4*>(Bt + (size_t)(n0 + row) * K + kt + ko);
            *reinterpret_cast<uint4*>(&Bs[row][ko]) = v;
        }
        __syncthreads();
#pragma unroll
        for (int ks = 0; ks < 2; ks++) {
            short8 b[2];
#pragma unroll
            for (int ni = 0; ni < 2; ni++)
                b[ni] = *reinterpret_cast<const short8*>(&Bs[wc * 32 + ni * 16 + l15][ks * 32 + kg]);
#pragma unroll
            for (int mi = 0; mi < 4; mi++) {
                short8 a = *reinterpret_cast<const short8*>(&As[wr * 64 + mi * 16 + l15][ks * 32 + kg]);
#pragma unroll
                for (int ni = 0; ni < 2; ni++)
                    acc[mi][ni] = __builtin_amdgcn_mfma_f32_16x16x32_bf16(a, b[ni], acc[mi][ni], 0, 0, 0);
            }
        }
        __syncthreads();
    }
    int rbase = (lane >> 4) * 4;
#pragma unroll
    for (int mi = 0; mi < 4; mi++)
#pragma unroll
        for (int ni = 0; ni < 2; ni++) {
            int n = wc * 32 + ni * 16 + l15;
            float bn = bias[n];
#pragma unroll
            for (int r = 0; r < 4; r++) {
                int m = m0 + wr * 64 + mi * 16 + rbase + r;
                out[(size_t)m * 64 + n] = acc[mi][ni][r] + bn;
            }
        }
}

// ---------------------------------------------------------------------------

extern "C" void kernel_launch(void* const* d_in, const int* in_sizes, int n_in,
                              void* d_out, int out_size, void* d_ws, size_t ws_size,
                              hipStream_t stream)
{
    const float* embed  = (const float*)d_in[0];
    const float* temp   = (const float*)d_in[1];
    const float* attn_w = (const float*)d_in[2];
    const float* attn_b = (const float*)d_in[3];
    const float* W1     = (const float*)d_in[4];
    const float* b1     = (const float*)d_in[5];
    const float* W2     = (const float*)d_in[6];
    const float* b2     = (const float*)d_in[7];
    const int*   ei     = (const int*)d_in[8];
    const int*   H_idx  = (const int*)d_in[9];
    const int*   H_seg  = (const int*)d_in[10];
    const int*   T_idx  = (const int*)d_in[11];
    const int*   T_seg  = (const int*)d_in[12];

    const int D     = in_sizes[2];        // 128
    const int N     = in_sizes[0] / D;    // 100000
    const int Khops = in_sizes[1] - 1;    // 3
    const int E     = in_sizes[8] / 2;    // 1600000
    const int L     = in_sizes[9];        // 262144
    const int R     = in_sizes[7];        // 64
    const int HMLP  = in_sizes[5];        // 512
    const int Bb    = out_size / R;       // 32768

    const int* srcI = ei;
    const int* dstI = ei + E;

    // ---- workspace carve (256B aligned) ----
    char* ws = (char*)d_ws;
    size_t off = 0;
    auto carve = [&](size_t bytes) -> char* {
        char* p = ws + off;
        off += (bytes + 255) & ~(size_t)255;
        return p;
    };

    int nblk = DIV_UP(N, 1024);
    int*   deg_src  = (int*)carve((size_t)N * 4);
    int*   deg_dst  = (int*)carve((size_t)N * 4);
    int*   incl     = (int*)carve((size_t)N * 4);
    int*   bsums    = (int*)carve((size_t)nblk * 4);
    int*   bsumex   = (int*)carve((size_t)nblk * 4);
    int*   rowptr   = (int*)carve((size_t)(N + 1) * 4);
    int*   cursor   = (int*)carve((size_t)N * 4);
    int*   csr_src  = (int*)carve((size_t)E * 4);
    float* csr_norm = (float*)carve((size_t)E * 4);
    float* xA       = (float*)carve((size_t)N * D * 4);
    float* xB       = (float*)carve((size_t)N * D * 4);
    float* hiddenZ  = (float*)carve((size_t)N * D * 4);
    float* sH       = (float*)carve((size_t)L * 4);
    float* sT       = (float*)carve((size_t)L * 4);
    int*   segH     = (int*)carve((size_t)(Bb + 1) * 4);
    int*   segT     = (int*)carve((size_t)(Bb + 1) * 4);
    float* hPool    = (float*)carve((size_t)Bb * D * 4);
    float* tPool    = (float*)carve((size_t)Bb * D * 4);
    unsigned short* W1Tb = (unsigned short*)carve((size_t)HMLP * 384 * 2);
    unsigned short* W2Tb = (unsigned short*)carve((size_t)R * HMLP * 2);
    // bf16 feats [Bb x 384] (25.2MB) and hid [Bb x 512] (33.6MB) overlap the
    // x ping-pong buffers, which are dead after the last hop (each 51.2MB).
    unsigned short* featsB = (unsigned short*)xB;
    unsigned short* hidB   = (unsigned short*)xA;

    hipMemsetAsync(deg_src, 0, (size_t)N * 4, stream);
    hipMemsetAsync(deg_dst, 0, (size_t)N * 4, stream);

    deg_kernel<<<DIV_UP(E, 256), 256, 0, stream>>>(srcI, dstI, deg_src, deg_dst, E);
    scanA_kernel<<<nblk, 256, 0, stream>>>(deg_dst, incl, bsums, N);
    scanB_kernel<<<1, 64, 0, stream>>>(bsums, bsumex, nblk);
    scanC_kernel<<<DIV_UP(N + 1, 256), 256, 0, stream>>>(incl, deg_dst, bsumex, rowptr, cursor, N, E);
    scatter_kernel<<<DIV_UP(E, 256), 256, 0, stream>>>(srcI, dstI, deg_src, deg_dst, cursor,
                                                       csr_src, csr_norm, E);
    rowsort_kernel<<<DIV_UP(N * 64, 256), 256, 0, stream>>>(rowptr, csr_src, csr_norm, N);
    init_hidden_kernel<<<DIV_UP(N * D / 4, 256), 256, 0, stream>>>(
        (const float4*)embed, (float4*)hiddenZ, temp, N * D / 4);

    const float* xin = embed;
    float* xout = xA;
    for (int k = 0; k < Khops; k++) {
        hop_kernel<<<DIV_UP(N * 32, 256), 256, 0, stream>>>(
            xin, xout, hiddenZ, rowptr, csr_src, csr_norm, temp, k + 1, N);
        xin  = xout;
        xout = (xout == xA) ? xB : xA;
    }
    // after 3 hops: xA holds x_3, xB holds x_2 -> both dead below.

    segstart_kernel<<<DIV_UP(Bb + 1, 256), 256, 0, stream>>>(H_seg, segH, L, Bb);
    segstart_kernel<<<DIV_UP(Bb + 1, 256), 256, 0, stream>>>(T_seg, segT, L, Bb);
    score_kernel<<<DIV_UP(L * 64, 256), 256, 0, stream>>>(hiddenZ, H_idx, attn_w, attn_b, sH, L);
    score_kernel<<<DIV_UP(L * 64, 256), 256, 0, stream>>>(hiddenZ, T_idx, attn_w, attn_b, sT, L);
    pool_kernel<<<DIV_UP(Bb * 64, 256), 256, 0, stream>>>(hiddenZ, H_idx, sH, segH, hPool, Bb);
    pool_kernel<<<DIV_UP(Bb * 64, 256), 256, 0, stream>>>(hiddenZ, T_idx, sT, segT, tPool, Bb);

    convT_kernel<<<DIV_UP(384 * HMLP, 256), 256, 0, stream>>>(W1, W1Tb, 384, HMLP);
    convT_kernel<<<DIV_UP(HMLP * R, 256), 256, 0, stream>>>(W2, W2Tb, HMLP, R);
    feats_kernel<<<DIV_UP(Bb * 384, 256), 256, 0, stream>>>(hPool, tPool, featsB, Bb);

    gemm1_mfma<<<dim3(HMLP / 64, Bb / 128), 256, 0, stream>>>(featsB, W1Tb, b1, hidB);
    gemm2_mfma<<<dim3(1, Bb / 128), 256, 0, stream>>>(hidB, W2Tb, b2, (float*)d_out);
}

// Round 16
// 1027.894 us; speedup vs baseline: 1.3365x; 1.0267x over previous
//
#include <hip/hip_runtime.h>
#include <hip/hip_bf16.h>
#include <math.h>

#define DIV_UP(a,b) (((a)+(b)-1)/(b))

typedef __attribute__((ext_vector_type(8))) short short8;
typedef __attribute__((ext_vector_type(4))) float floatx4;

static __device__ __forceinline__ unsigned short f2bf(float f)
{
    union { float f; unsigned int u; } v; v.f = f;
    unsigned int u = v.u;
    return (unsigned short)((u + 0x7fffu + ((u >> 16) & 1u)) >> 16);
}

// ---------------------------------------------------------------------------
// Graph prep: degrees, prefix scan -> rowptr, packed CSR scatter (+ sort)
// ---------------------------------------------------------------------------

__global__ void deg_kernel(const int* __restrict__ src, const int* __restrict__ dst,
                           int* __restrict__ deg_src, int* __restrict__ deg_dst, int E)
{
    int e = blockIdx.x * blockDim.x + threadIdx.x;
    if (e >= E) return;
    atomicAdd(&deg_src[src[e]], 1);
    atomicAdd(&deg_dst[dst[e]], 1);
}

// Block-level inclusive scan over chunks of 1024 ints (256 threads x 4).
__global__ void scanA_kernel(const int* __restrict__ deg, int* __restrict__ incl,
                             int* __restrict__ bsums, int n)
{
    __shared__ int sdata[256];
    int t = threadIdx.x;
    int base = blockIdx.x * 1024 + t * 4;
    int v[4];
    int s = 0;
#pragma unroll
    for (int i = 0; i < 4; i++) {
        int x = (base + i < n) ? deg[base + i] : 0;
        s += x;
        v[i] = s;                // inclusive within thread
    }
    sdata[t] = s;
    __syncthreads();
#pragma unroll
    for (int off = 1; off < 256; off <<= 1) {
        int x = (t >= off) ? sdata[t - off] : 0;
        __syncthreads();
        sdata[t] += x;
        __syncthreads();
    }
    int prev = (t > 0) ? sdata[t - 1] : 0;
#pragma unroll
    for (int i = 0; i < 4; i++)
        if (base + i < n) incl[base + i] = prev + v[i];
    if (t == 255) bsums[blockIdx.x] = sdata[255];
}

__global__ void scanB_kernel(const int* __restrict__ bsums, int* __restrict__ bsumex, int nblk)
{
    if (blockIdx.x == 0 && threadIdx.x == 0) {
        int run = 0;
        for (int i = 0; i < nblk; i++) { int v = bsums[i]; bsumex[i] = run; run += v; }
    }
}

__global__ void scanC_kernel(const int* __restrict__ incl, const int* __restrict__ deg,
                             const int* __restrict__ bsumex,
                             int* __restrict__ rowptr, int* __restrict__ cursor,
                             int n, int total)
{
    int i = blockIdx.x * blockDim.x + threadIdx.x;
    if (i > n) return;
    if (i == n) { rowptr[n] = total; return; }
    int r = incl[i] - deg[i] + bsumex[i >> 10];   // exclusive prefix
    rowptr[i] = r;
    cursor[i] = r;
}

// Packed CSR entry: {src, norm bit-cast}. One 8B load per edge in the hop.
__global__ void scatter_kernel(const int* __restrict__ src, const int* __restrict__ dst,
                               const int* __restrict__ deg_src, const int* __restrict__ deg_dst,
                               int* __restrict__ cursor, int2* __restrict__ csr, int E)
{
    int e = blockIdx.x * blockDim.x + threadIdx.x;
    if (e >= E) return;
    int s = src[e], d = dst[e];
    float ns = rsqrtf(fmaxf((float)deg_src[s], 1.f));
    float nd = rsqrtf(fmaxf((float)deg_dst[d], 1.f));
    int pos = atomicAdd(&cursor[d], 1);
    csr[pos] = make_int2(s, __float_as_int(ns * nd));
}

// Canonicalize row order (atomic scatter order is nondeterministic run-to-run;
// fp32 sum order must be a pure function of the inputs). One 64-lane wave per
// row: lane i holds element i, rank via wave-uniform shfl loop, write beg+rank.
// Ranks unique (tie-break by lane); duplicate srcs carry identical norm.
// deg>64 falls back to lane-0 insertion sort (never taken at lambda=16).
__global__ void rowsort_kernel(const int* __restrict__ rowptr, int2* __restrict__ csr, int n)
{
    int wid = (blockIdx.x * blockDim.x + threadIdx.x) >> 6;
    if (wid >= n) return;
    int lane = threadIdx.x & 63;
    int beg = rowptr[wid], end = rowptr[wid + 1];
    int deg = end - beg;
    if (deg <= 1) return;
    if (deg <= 64) {
        int2 p = (lane < deg) ? csr[beg + lane] : make_int2(0x7fffffff, 0);
        int key = p.x;
        int rank = 0;
        for (int j = 0; j < deg; j++) {           // deg is wave-uniform
            int kj = __shfl(key, j, 64);
            rank += (kj < key) || (kj == key && j < lane);
        }
        if (lane < deg) csr[beg + rank] = p;
    } else if (lane == 0) {
        for (int i = beg + 1; i < end; ++i) {
            int2 p = csr[i];
            int j = i - 1;
            while (j >= beg && csr[j].x > p.x) { csr[j + 1] = csr[j]; --j; }
            csr[j + 1] = p;
        }
    }
}

// ---------------------------------------------------------------------------
// Propagation
// ---------------------------------------------------------------------------

__global__ void init_hidden_kernel(const float4* __restrict__ embed, float4* __restrict__ hidden,
                                   const float* __restrict__ temp, int n4)
{
    int i = blockIdx.x * blockDim.x + threadIdx.x;
    if (i >= n4) return;
    float t0 = temp[0];
    float4 v = embed[i];
    v.x *= t0; v.y *= t0; v.z *= t0; v.w *= t0;
    hidden[i] = v;
}

// One 32-lane group per node; lane owns one float4 chunk of the 128-d row.
// Edge loop unrolled x4: 4 independent gathers in flight per lane (MLP);
// accumulation stays sequential in j order -> numerics identical to the
// non-unrolled loop (only load issue order changes).
__global__ void hop_kernel(const float* __restrict__ xin, float* __restrict__ xout,
                           float* __restrict__ hidden,
                           const int* __restrict__ rowptr, const int2* __restrict__ csr,
                           const float* __restrict__ temp, int kidx, int n)
{
    int gid = blockIdx.x * blockDim.x + threadIdx.x;
    int node = gid >> 5;
    if (node >= n) return;
    int c = (gid & 31) * 4;
    float tk = temp[kidx];
    int beg = rowptr[node], end = rowptr[node + 1];
    float ax = 0.f, ay = 0.f, az = 0.f, aw = 0.f;
    int j = beg;
    for (; j + 4 <= end; j += 4) {
        int2 p0 = csr[j], p1 = csr[j + 1], p2 = csr[j + 2], p3 = csr[j + 3];
        const float4 v0 = *reinterpret_cast<const float4*>(xin + (size_t)p0.x * 128 + c);
        const float4 v1 = *reinterpret_cast<const float4*>(xin + (size_t)p1.x * 128 + c);
        const float4 v2 = *reinterpret_cast<const float4*>(xin + (size_t)p2.x * 128 + c);
        const float4 v3 = *reinterpret_cast<const float4*>(xin + (size_t)p3.x * 128 + c);
        float w0 = __int_as_float(p0.y), w1 = __int_as_float(p1.y);
        float w2 = __int_as_float(p2.y), w3 = __int_as_float(p3.y);
        ax += w0 * v0.x; ay += w0 * v0.y; az += w0 * v0.z; aw += w0 * v0.w;
        ax += w1 * v1.x; ay += w1 * v1.y; az += w1 * v1.z; aw += w1 * v1.w;
        ax += w2 * v2.x; ay += w2 * v2.y; az += w2 * v2.z; aw += w2 * v2.w;
        ax += w3 * v3.x; ay += w3 * v3.y; az += w3 * v3.z; aw += w3 * v3.w;
    }
    for (; j < end; ++j) {
        int2 p = csr[j];
        float w = __int_as_float(p.y);
        const float4 v = *reinterpret_cast<const float4*>(xin + (size_t)p.x * 128 + c);
        ax += w * v.x; ay += w * v.y; az += w * v.z; aw += w * v.w;
    }
    size_t o = (size_t)node * 128 + c;
    *reinterpret_cast<float4*>(xout + o) = make_float4(ax, ay, az, aw);
    float4* ph = reinterpret_cast<float4*>(hidden + o);
    float4 h = *ph;
    h.x += tk * ax; h.y += tk * ay; h.z += tk * az; h.w += tk * aw;
    *ph = h;
}

// ---------------------------------------------------------------------------
// Attention pooling
// ---------------------------------------------------------------------------

__global__ void segstart_kernel(const int* __restrict__ seg, int* __restrict__ out, int L, int B)
{
    int b = blockIdx.x * blockDim.x + threadIdx.x;
    if (b > B) return;
    int lo = 0, hi = L;
    while (lo < hi) { int mid = (lo + hi) >> 1; if (seg[mid] < b) lo = mid + 1; else hi = mid; }
    out[b] = lo;
}

__global__ void score_kernel(const float* __restrict__ z, const int* __restrict__ idx,
                             const float* __restrict__ attn_w, const float* __restrict__ attn_b,
                             float* __restrict__ s, int L)
{
    int gid = blockIdx.x * blockDim.x + threadIdx.x;
    int l = gid >> 6;
    if (l >= L) return;
    int lane = threadIdx.x & 63;
    int node = idx[l];
    const float2 v = *reinterpret_cast<const float2*>(z + (size_t)node * 128 + lane * 2);
    const float2 w = *reinterpret_cast<const float2*>(attn_w + lane * 2);
    float p = v.x * w.x + v.y * w.y;
#pragma unroll
    for (int off = 32; off > 0; off >>= 1) p += __shfl_down(p, off, 64);
    if (lane == 0) s[l] = p + attn_b[0];
}

__global__ void pool_kernel(const float* __restrict__ z, const int* __restrict__ idx,
                            const float* __restrict__ s, const int* __restrict__ segstart,
                            float* __restrict__ out, int B)
{
    int gid = blockIdx.x * blockDim.x + threadIdx.x;
    int b = gid >> 6;
    if (b >= B) return;
    int lane = threadIdx.x & 63;
    int beg = segstart[b], end = segstart[b + 1];
    float accx = 0.f, accy = 0.f;
    if (end > beg) {
        float m = -1e30f;
        for (int j = beg; j < end; ++j) m = fmaxf(m, s[j]);
        float denom = 0.f;
        for (int j = beg; j < end; ++j) {
            float e = expf(s[j] - m);
            denom += e;
            int node = idx[j];
            const float2 v = *reinterpret_cast<const float2*>(z + (size_t)node * 128 + lane * 2);
            accx += e * v.x; accy += e * v.y;
        }
        float inv = 1.f / denom;
        accx *= inv; accy *= inv;
    }
    float2* po = reinterpret_cast<float2*>(out + (size_t)b * 128 + lane * 2);
    *po = make_float2(accx, accy);
}

// ---------------------------------------------------------------------------
// MLP in bf16 MFMA: feats = [h,t,h*t] bf16; hid = relu(feats@W1+b1) bf16;
// out = hid@W2 + b2 (f32).
// ---------------------------------------------------------------------------

// src[K][N] f32 -> dst[N][K] bf16 (transpose + convert)
__global__ void convT_kernel(const float* __restrict__ src, unsigned short* __restrict__ dst,
                             int K, int N)
{
    int i = blockIdx.x * blockDim.x + threadIdx.x;
    if (i >= K * N) return;
    int k = i / N, n = i % N;
    dst[(size_t)n * K + k] = f2bf(src[i]);
}

__global__ void feats_kernel(const float* __restrict__ hP, const float* __restrict__ tP,
                             unsigned short* __restrict__ feats, int M)
{
    int i = blockIdx.x * blockDim.x + threadIdx.x;
    if (i >= M * 384) return;
    int m = i / 384, k = i % 384;
    float v;
    if (k < 128)      v = hP[(size_t)m * 128 + k];
    else if (k < 256) v = tP[(size_t)m * 128 + (k - 128)];
    else { int kk = k - 256; v = hP[(size_t)m * 128 + kk] * tP[(size_t)m * 128 + kk]; }
    feats[i] = f2bf(v);
}

// C[m][n] = relu(A[m][:] . BT[n][:] + bias[n]) -> bf16. A:[M][384], BT:[512][384].
// Block tile 128x64, 4 waves (2x2), wave tile 64x32 = 4x2 frags of 16x16x32.
__global__ __launch_bounds__(256) void gemm1_mfma(const unsigned short* __restrict__ A,
                                                  const unsigned short* __restrict__ Bt,
                                                  const float* __restrict__ bias,
                                                  unsigned short* __restrict__ C)
{
    const int K = 384;
    __shared__ short As[128][72];   // pad 64->72 shorts: 2-way bank alias only
    __shared__ short Bs[64][72];
    int tid = threadIdx.x;
    int lane = tid & 63, wave = tid >> 6;
    int wr = wave >> 1, wc = wave & 1;
    int m0 = blockIdx.y * 128, n0 = blockIdx.x * 64;
    int l15 = lane & 15, kg = (lane >> 4) * 8;

    floatx4 zero = {0.f, 0.f, 0.f, 0.f};
    floatx4 acc[4][2];
#pragma unroll
    for (int mi = 0; mi < 4; mi++)
#pragma unroll
        for (int ni = 0; ni < 2; ni++) acc[mi][ni] = zero;

    for (int kt = 0; kt < K; kt += 64) {
#pragma unroll
        for (int i = 0; i < 4; i++) {              // A tile: 128 rows x 64 k
            int c = tid + 256 * i;
            int row = c >> 3, ko = (c & 7) * 8;
            uint4 v = *reinterpret_cast<const uint4*>(A + (size_t)(m0 + row) * K + kt + ko);
            *reinterpret_cast<uint4*>(&As[row][ko]) = v;
        }
#pragma unroll
        for (int i = 0; i < 2; i++) {              // B tile: 64 rows x 64 k
            int c = tid + 256 * i;
            int row = c >> 3, ko = (c & 7) * 8;
            uint4 v = *reinterpret_cast<const uint4*>(Bt + (size_t)(n0 + row) * K + kt + ko);
            *reinterpret_cast<uint4*>(&Bs[row][ko]) = v;
        }
        __syncthreads();
#pragma unroll
        for (int ks = 0; ks < 2; ks++) {
            short8 b[2];
#pragma unroll
            for (int ni = 0; ni < 2; ni++)
                b[ni] = *reinterpret_cast<const short8*>(&Bs[wc * 32 + ni * 16 + l15][ks * 32 + kg]);
#pragma unroll
            for (int mi = 0; mi < 4; mi++) {
                short8 a = *reinterpret_cast<const short8*>(&As[wr * 64 + mi * 16 + l15][ks * 32 + kg]);
#pragma unroll
                for (int ni = 0; ni < 2; ni++)
                    acc[mi][ni] = __builtin_amdgcn_mfma_f32_16x16x32_bf16(a, b[ni], acc[mi][ni], 0, 0, 0);
            }
        }
        __syncthreads();
    }
    int rbase = (lane >> 4) * 4;
#pragma unroll
    for (int mi = 0; mi < 4; mi++)
#pragma unroll
        for (int ni = 0; ni < 2; ni++) {
            int n = n0 + wc * 32 + ni * 16 + l15;
            float bn = bias[n];
#pragma unroll
            for (int r = 0; r < 4; r++) {
                int m = m0 + wr * 64 + mi * 16 + rbase + r;
                float v = acc[mi][ni][r] + bn;
                v = v > 0.f ? v : 0.f;
                C[(size_t)m * 512 + n] = f2bf(v);
            }
        }
}

// out[m][n] = A[m][:] . BT[n][:] + bias[n] (f32). A:[M][512] bf16, BT:[64][512] bf16.
__global__ __launch_bounds__(256) void gemm2_mfma(const unsigned short* __restrict__ A,
                                                  const unsigned short* __restrict__ Bt,
                                                  const float* __restrict__ bias,
                                                  float* __restrict__ out)
{
    const int K = 512;
    __shared__ short As[128][72];
    __shared__ short Bs[64][72];
    int tid = threadIdx.x;
    int lane = tid & 63, wave = tid >> 6;
    int wr = wave >> 1, wc = wave & 1;
    int m0 = blockIdx.y * 128, n0 = 0;
    int l15 = lane & 15, kg = (lane >> 4) * 8;

    floatx4 zero = {0.f, 0.f, 0.f, 0.f};
    floatx4 acc[4][2];
#pragma unroll
    for (int mi = 0; mi < 4; mi++)
#pragma unroll
        for (int ni = 0; ni < 2; ni++) acc[mi][ni] = zero;

    for (int kt = 0; kt < K; kt += 64) {
#pragma unroll
        for (int i = 0; i < 4; i++) {
            int c = tid + 256 * i;
            int row = c >> 3, ko = (c & 7) * 8;
            uint4 v = *reinterpret_cast<const uint4*>(A + (size_t)(m0 + row) * K + kt + ko);
            *reinterpret_cast<uint4*>(&As[row][ko]) = v;
        }
#pragma unroll
        for (int i = 0; i < 2; i++) {
            int c = tid + 256 * i;
            int row = c >> 3, ko = (c & 7) * 8;
            uint4 v = *reinterpret_cast<const uint4*>(Bt + (size_t)(n0 + row) * K + kt + ko);
            *reinterpret_cast<uint4*>(&Bs[row][ko]) = v;
        }
        __syncthreads();
#pragma unroll
        for (int ks = 0; ks < 2; ks++) {
            short8 b[2];
#pragma unroll
            for (int ni = 0; ni < 2; ni++)
                b[ni] = *reinterpret_cast<const short8*>(&Bs[wc * 32 + ni * 16 + l15][ks * 32 + kg]);
#pragma unroll
            for (int mi = 0; mi < 4; mi++) {
                short8 a = *reinterpret_cast<const short8*>(&As[wr * 64 + mi * 16 + l15][ks * 32 + kg]);
#pragma unroll
                for (int ni = 0; ni < 2; ni++)
                    acc[mi][ni] = __builtin_amdgcn_mfma_f32_16x16x32_bf16(a, b[ni], acc[mi][ni], 0, 0, 0);
            }
        }
        __syncthreads();
    }
    int rbase = (lane >> 4) * 4;
#pragma unroll
    for (int mi = 0; mi < 4; mi++)
#pragma unroll
        for (int ni = 0; ni < 2; ni++) {
            int n = wc * 32 + ni * 16 + l15;
            float bn = bias[n];
#pragma unroll
            for (int r = 0; r < 4; r++) {
                int m = m0 + wr * 64 + mi * 16 + rbase + r;
                out[(size_t)m * 64 + n] = acc[mi][ni][r] + bn;
            }
        }
}

// ---------------------------------------------------------------------------

extern "C" void kernel_launch(void* const* d_in, const int* in_sizes, int n_in,
                              void* d_out, int out_size, void* d_ws, size_t ws_size,
                              hipStream_t stream)
{
    const float* embed  = (const float*)d_in[0];
    const float* temp   = (const float*)d_in[1];
    const float* attn_w = (const float*)d_in[2];
    const float* attn_b = (const float*)d_in[3];
    const float* W1     = (const float*)d_in[4];
    const float* b1     = (const float*)d_in[5];
    const float* W2     = (const float*)d_in[6];
    const float* b2     = (const float*)d_in[7];
    const int*   ei     = (const int*)d_in[8];
    const int*   H_idx  = (const int*)d_in[9];
    const int*   H_seg  = (const int*)d_in[10];
    const int*   T_idx  = (const int*)d_in[11];
    const int*   T_seg  = (const int*)d_in[12];

    const int D     = in_sizes[2];        // 128
    const int N     = in_sizes[0] / D;    // 100000
    const int Khops = in_sizes[1] - 1;    // 3
    const int E     = in_sizes[8] / 2;    // 1600000
    const int L     = in_sizes[9];        // 262144
    const int R     = in_sizes[7];        // 64
    const int HMLP  = in_sizes[5];        // 512
    const int Bb    = out_size / R;       // 32768

    const int* srcI = ei;
    const int* dstI = ei + E;

    // ---- workspace carve (256B aligned) ----
    char* ws = (char*)d_ws;
    size_t off = 0;
    auto carve = [&](size_t bytes) -> char* {
        char* p = ws + off;
        off += (bytes + 255) & ~(size_t)255;
        return p;
    };

    int nblk = DIV_UP(N, 1024);
    int*   deg_src  = (int*)carve((size_t)N * 4);
    int*   deg_dst  = (int*)carve((size_t)N * 4);
    int*   incl     = (int*)carve((size_t)N * 4);
    int*   bsums    = (int*)carve((size_t)nblk * 4);
    int*   bsumex   = (int*)carve((size_t)nblk * 4);
    int*   rowptr   = (int*)carve((size_t)(N + 1) * 4);
    int*   cursor   = (int*)carve((size_t)N * 4);
    int2*  csr      = (int2*)carve((size_t)E * 8);
    float* xA       = (float*)carve((size_t)N * D * 4);
    float* xB       = (float*)carve((size_t)N * D * 4);
    float* hiddenZ  = (float*)carve((size_t)N * D * 4);
    float* sH       = (float*)carve((size_t)L * 4);
    float* sT       = (float*)carve((size_t)L * 4);
    int*   segH     = (int*)carve((size_t)(Bb + 1) * 4);
    int*   segT     = (int*)carve((size_t)(Bb + 1) * 4);
    float* hPool    = (float*)carve((size_t)Bb * D * 4);
    float* tPool    = (float*)carve((size_t)Bb * D * 4);
    unsigned short* W1Tb = (unsigned short*)carve((size_t)HMLP * 384 * 2);
    unsigned short* W2Tb = (unsigned short*)carve((size_t)R * HMLP * 2);
    // bf16 feats [Bb x 384] (25.2MB) and hid [Bb x 512] (33.6MB) overlap the
    // x ping-pong buffers, which are dead after the last hop (each 51.2MB).
    unsigned short* featsB = (unsigned short*)xB;
    unsigned short* hidB   = (unsigned short*)xA;

    hipMemsetAsync(deg_src, 0, (size_t)N * 4, stream);
    hipMemsetAsync(deg_dst, 0, (size_t)N * 4, stream);

    deg_kernel<<<DIV_UP(E, 256), 256, 0, stream>>>(srcI, dstI, deg_src, deg_dst, E);
    scanA_kernel<<<nblk, 256, 0, stream>>>(deg_dst, incl, bsums, N);
    scanB_kernel<<<1, 64, 0, stream>>>(bsums, bsumex, nblk);
    scanC_kernel<<<DIV_UP(N + 1, 256), 256, 0, stream>>>(incl, deg_dst, bsumex, rowptr, cursor, N, E);
    scatter_kernel<<<DIV_UP(E, 256), 256, 0, stream>>>(srcI, dstI, deg_src, deg_dst, cursor, csr, E);
    rowsort_kernel<<<DIV_UP(N * 64, 256), 256, 0, stream>>>(rowptr, csr, N);
    init_hidden_kernel<<<DIV_UP(N * D / 4, 256), 256, 0, stream>>>(
        (const float4*)embed, (float4*)hiddenZ, temp, N * D / 4);

    const float* xin = embed;
    float* xout = xA;
    for (int k = 0; k < Khops; k++) {
        hop_kernel<<<DIV_UP(N * 32, 256), 256, 0, stream>>>(
            xin, xout, hiddenZ, rowptr, csr, temp, k + 1, N);
        xin  = xout;
        xout = (xout == xA) ? xB : xA;
    }
    // after 3 hops: xA holds x_3, xB holds x_2 -> both dead below.

    segstart_kernel<<<DIV_UP(Bb + 1, 256), 256, 0, stream>>>(H_seg, segH, L, Bb);
    segstart_kernel<<<DIV_UP(Bb + 1, 256), 256, 0, stream>>>(T_seg, segT, L, Bb);
    score_kernel<<<DIV_UP(L * 64, 256), 256, 0, stream>>>(hiddenZ, H_idx, attn_w, attn_b, sH, L);
    score_kernel<<<DIV_UP(L * 64, 256), 256, 0, stream>>>(hiddenZ, T_idx, attn_w, attn_b, sT, L);
    pool_kernel<<<DIV_UP(Bb * 64, 256), 256, 0, stream>>>(hiddenZ, H_idx, sH, segH, hPool, Bb);
    pool_kernel<<<DIV_UP(Bb * 64, 256), 256, 0, stream>>>(hiddenZ, T_idx, sT, segT, tPool, Bb);

    convT_kernel<<<DIV_UP(384 * HMLP, 256), 256, 0, stream>>>(W1, W1Tb, 384, HMLP);
    convT_kernel<<<DIV_UP(HMLP * R, 256), 256, 0, stream>>>(W2, W2Tb, HMLP, R);
    feats_kernel<<<DIV_UP(Bb * 384, 256), 256, 0, stream>>>(hPool, tPool, featsB, Bb);

    gemm1_mfma<<<dim3(HMLP / 64, Bb / 128), 256, 0, stream>>>(featsB, W1Tb, b1, hidB);
    gemm2_mfma<<<dim3(1, Bb / 128), 256, 0, stream>>>(hidB, W2Tb, b2, (float*)d_out);
}